// Round 14
// baseline (235.594 us; speedup 1.0000x reference)
//
#include <hip/hip_runtime.h>
#include <hip/hip_bf16.h>

#define NN 100000
#define NE 1600000
#define NBUCK 391   // ceil(NN / 256)
#define CAP 5120    // per-bucket edge capacity (expected 4096, sigma~64)
#define CHUNK 2048
#define PBLOCKS 782   // ceil(NE / CHUNK)
#define MMBLOCKS 1563 // ceil(NN / 64)

typedef __attribute__((ext_vector_type(8))) short short8;
typedef __attribute__((ext_vector_type(4))) float f32x4;

static __device__ __forceinline__ unsigned short f2bf(float f) {
    unsigned u = __float_as_uint(f);
    unsigned r = (u + 0x7fffu + ((u >> 16) & 1u)) >> 16;
    return (unsigned short)r;
}
static __device__ __forceinline__ float bf_lo(unsigned u) {
    return __uint_as_float(u << 16);
}
static __device__ __forceinline__ float bf_hi(unsigned u) {
    return __uint_as_float(u & 0xffff0000u);
}
static __device__ __forceinline__ void acc16(float* acc, uint4 a, uint4 b, float nm) {
    acc[0]  += bf_lo(a.x) * nm; acc[1]  += bf_hi(a.x) * nm;
    acc[2]  += bf_lo(a.y) * nm; acc[3]  += bf_hi(a.y) * nm;
    acc[4]  += bf_lo(a.z) * nm; acc[5]  += bf_hi(a.z) * nm;
    acc[6]  += bf_lo(a.w) * nm; acc[7]  += bf_hi(a.w) * nm;
    acc[8]  += bf_lo(b.x) * nm; acc[9]  += bf_hi(b.x) * nm;
    acc[10] += bf_lo(b.y) * nm; acc[11] += bf_hi(b.y) * nm;
    acc[12] += bf_lo(b.z) * nm; acc[13] += bf_hi(b.z) * nm;
    acc[14] += bf_lo(b.w) * nm; acc[15] += bf_hi(b.w) * nm;
}

// aggregation loop, 4 lanes/node: lane covers 16 cols (2 x uint4), unroll-2
static __device__ __forceinline__ void agg_loop16(const unsigned short* hc,
                                                  const int* __restrict__ esrc,
                                                  const float* __restrict__ dinv,
                                                  int start, int cnt, float dn,
                                                  float* acc) {
    int i = 0;
    for (; i + 2 <= cnt; i += 2) {
        int s0 = esrc[start + i];
        int s1 = esrc[start + i + 1];
        float n0 = dinv[s0] * dn, n1 = dinv[s1] * dn;
        const uint4* p0 = (const uint4*)(hc + (long)s0 * 64);
        const uint4* p1 = (const uint4*)(hc + (long)s1 * 64);
        uint4 a0 = p0[0], b0 = p0[1];
        uint4 a1 = p1[0], b1 = p1[1];
        acc16(acc, a0, b0, n0);
        acc16(acc, a1, b1, n1);
    }
    if (i < cnt) {
        int s0 = esrc[start + i];
        float n0 = dinv[s0] * dn;
        const uint4* p0 = (const uint4*)(hc + (long)s0 * 64);
        uint4 a0 = p0[0], b0 = p0[1];
        acc16(acc, a0, b0, n0);
    }
}

// ---------- FAT: blocks [0,PBLOCKS) = edge partition (1-pass); rest = x@W1 ----
// bucket = dst >> 8; pack = (src<<8)|(dst&255)
__global__ __launch_bounds__(256) void k_fat(const int* __restrict__ ei,
                                             int* __restrict__ bcur,
                                             unsigned* __restrict__ ebuf,
                                             const float* __restrict__ x,
                                             const float* __restrict__ W1,
                                             unsigned short* __restrict__ hout) {
    __shared__ __attribute__((aligned(16))) unsigned char smem[17408];  // max(mm Wt 64*136*2, part 2*391*4)
    int tid = threadIdx.x;
    if (blockIdx.x < PBLOCKS) {
        int* lh = (int*)smem;
        int* lbase = lh + NBUCK;
        int e0 = blockIdx.x * CHUNK;
        for (int i = tid; i < NBUCK; i += 256) lh[i] = 0;
        __syncthreads();
        int bs[8]; int rs[8]; unsigned ps[8];
        #pragma unroll
        for (int k = 0; k < 8; ++k) {
            int e = e0 + k * 256 + tid;
            bs[k] = -1;
            if (e < NE) {
                int d = ei[NE + e];
                int s = ei[e];
                int b = d >> 8;
                bs[k] = b;
                rs[k] = atomicAdd(&lh[b], 1);      // local rank (single LDS pass)
                ps[k] = ((unsigned)s << 8) | (unsigned)(d & 255);
            }
        }
        __syncthreads();
        for (int i = tid; i < NBUCK; i += 256) {
            int c = lh[i];
            lbase[i] = c ? atomicAdd(&bcur[i], c) : 0;  // within-bucket offset
        }
        __syncthreads();
        #pragma unroll
        for (int k = 0; k < 8; ++k) {
            if (bs[k] >= 0) {
                int pos = lbase[bs[k]] + rs[k];
                if (pos < CAP)  // safety clamp; never hit for uniform input
                    ebuf[(long)bs[k] * CAP + pos] = ps[k];
            }
        }
    } else {
        // ---- mm128: h1 = x @ W1 -> bf16 ----
        constexpr int K = 128, KP = K + 8;
        unsigned short* Wt = (unsigned short*)smem;  // 64 * 136
        for (int idx = tid; idx < K * 64; idx += 256) {
            int k = idx >> 6, n = idx & 63;
            Wt[n * KP + k] = f2bf(W1[idx]);
        }
        __syncthreads();
        int wave = tid >> 6, lane = tid & 63;
        int m = lane & 15, q = lane >> 4;
        int n0 = (blockIdx.x - PBLOCKS) * 64 + wave * 16;
        f32x4 acc[4] = {{0.f,0.f,0.f,0.f},{0.f,0.f,0.f,0.f},{0.f,0.f,0.f,0.f},{0.f,0.f,0.f,0.f}};
        int row = n0 + m;
        int rowc = row < NN ? row : NN - 1;
        const float* xr = x + (long)rowc * K;
        #pragma unroll
        for (int kk = 0; kk < K / 32; ++kk) {
            const float4* p = (const float4*)(xr + kk * 32 + q * 8);
            float4 v0 = p[0], v1 = p[1];
            float xv[8] = {v0.x, v0.y, v0.z, v0.w, v1.x, v1.y, v1.z, v1.w};
            short8 afrag;
            #pragma unroll
            for (int i2 = 0; i2 < 8; ++i2) afrag[i2] = (short)f2bf(xv[i2]);
            #pragma unroll
            for (int nt = 0; nt < 4; ++nt) {
                const short8* bp = (const short8*)&Wt[(nt * 16 + m) * KP + kk * 32 + q * 8];
                acc[nt] = __builtin_amdgcn_mfma_f32_16x16x32_bf16(afrag, *bp, acc[nt], 0, 0, 0);
            }
        }
        // D layout: col=lane&15, row=(lane>>4)*4+reg  [m89-verified]
        #pragma unroll
        for (int reg = 0; reg < 4; ++reg) {
            int node = n0 + q * 4 + reg;
            if (node < NN) {
                #pragma unroll
                for (int nt = 0; nt < 4; ++nt)
                    hout[(long)node * 64 + nt * 16 + m] = f2bf(acc[nt][reg]);
            }
        }
    }
}

// one block (256 thr) per bucket, single ebuf pass with register stash.
// rowinfo[node] = (start << 11) | degree   (start < 391*5120 < 2^21, deg < 2^11)
__global__ __launch_bounds__(256) void k_build(const int* __restrict__ bcur,
                                               const unsigned* __restrict__ ebuf,
                                               unsigned* __restrict__ rowinfo,
                                               float* __restrict__ dinv,
                                               int* __restrict__ esrc) {
    __shared__ int cnt[256];
    __shared__ int sstart[256];
    __shared__ int wsum[4];
    int tid = threadIdx.x;
    int base = blockIdx.x * CAP;
    int nedge = bcur[blockIdx.x];
    if (nedge > CAP) nedge = CAP;
    cnt[tid] = 0;
    __syncthreads();
    int st[20];      // (rank<<8) | dst_local, or -1
    int ssrc[20];    // src node id
    #pragma unroll
    for (int k = 0; k < 20; ++k) {
        int j = tid + k * 256;
        st[k] = -1;
        if (j < nedge) {
            unsigned p = ebuf[base + j];
            int dl = (int)(p & 255u);
            int r = atomicAdd(&cnt[dl], 1);
            st[k] = (r << 8) | dl;
            ssrc[k] = (int)(p >> 8);
        }
    }
    __syncthreads();
    int v = cnt[tid];
    int lane = tid & 63;
    int incl = v;
    #pragma unroll
    for (int off = 1; off < 64; off <<= 1) {
        int t = __shfl_up(incl, off, 64);
        if (lane >= off) incl += t;
    }
    if (lane == 63) wsum[tid >> 6] = incl;
    __syncthreads();
    if (tid == 0) {
        int a = 0;
        #pragma unroll
        for (int w = 0; w < 4; ++w) { int t = wsum[w]; wsum[w] = a; a += t; }
    }
    __syncthreads();
    int ex = incl - v + wsum[tid >> 6];
    int node = blockIdx.x * 256 + tid;
    if (node < NN) {
        rowinfo[node] = ((unsigned)(base + ex) << 11) | (unsigned)v;
        dinv[node] = rsqrtf((float)(v + 1));  // +1 self-loop
    }
    sstart[tid] = base + ex;
    __syncthreads();
    #pragma unroll
    for (int k = 0; k < 20; ++k) {
        if (st[k] >= 0)
            esrc[sstart[st[k] & 255] + (st[k] >> 8)] = ssrc[k];
    }
}

// ---------- fused: layer-1 agg (64 nodes/block, 4 lanes/node) + h2 = prelu(agg1)@W2
__global__ __launch_bounds__(256) void k_aggmm(const unsigned* __restrict__ rowinfo,
                                               const int* __restrict__ esrc,
                                               const unsigned short* __restrict__ h,
                                               const float* __restrict__ dinv,
                                               const float* __restrict__ bias,
                                               const float* __restrict__ alpha,
                                               const float* __restrict__ W2,
                                               unsigned short* __restrict__ hout2) {
    __shared__ unsigned short Wt[64 * 72];    // W2 staged: Wt[n*72+k]
    __shared__ unsigned short aggs[64 * 72];  // 64 node-rows of bf16 agg (+8 pad)
    int tid = threadIdx.x;
    for (int idx = tid; idx < 64 * 64; idx += 256) {
        int k = idx >> 6, n = idx & 63;
        Wt[n * 72 + k] = f2bf(W2[idx]);
    }
    int sl = tid & 3;                   // 16 cols per lane
    int ln = tid >> 2;                  // 0..63 local node
    int node = blockIdx.x * 64 + ln;
    bool active = node < NN;
    if (active) {
        unsigned u = rowinfo[node];
        int start = (int)(u >> 11);
        int cnt = (int)(u & 2047u);
        float dn = dinv[node];
        const unsigned short* hc = h + sl * 16;

        float acc[16];
        {   // self-loop
            const uint4* hp = (const uint4*)(hc + (long)node * 64);
            uint4 a = hp[0], b = hp[1];
            float d2 = dn * dn;
            #pragma unroll
            for (int j = 0; j < 16; ++j) acc[j] = 0.f;
            acc16(acc, a, b, d2);
        }
        agg_loop16(hc, esrc, dinv, start, cnt, dn, acc);

        // bias + PReLU on cols sl*16 .. sl*16+15
        #pragma unroll
        for (int g = 0; g < 4; ++g) {
            float4 bb = *(const float4*)(bias + sl * 16 + g * 4);
            float4 aa = *(const float4*)(alpha + sl * 16 + g * 4);
            float vb[4] = {bb.x, bb.y, bb.z, bb.w};
            float va[4] = {aa.x, aa.y, aa.z, aa.w};
            #pragma unroll
            for (int t = 0; t < 4; ++t) {
                float v = acc[g * 4 + t] + vb[t];
                acc[g * 4 + t] = v >= 0.f ? v : va[t] * v;
            }
        }
        uint4 pk0, pk1;
        pk0.x = (unsigned)f2bf(acc[0])  | ((unsigned)f2bf(acc[1])  << 16);
        pk0.y = (unsigned)f2bf(acc[2])  | ((unsigned)f2bf(acc[3])  << 16);
        pk0.z = (unsigned)f2bf(acc[4])  | ((unsigned)f2bf(acc[5])  << 16);
        pk0.w = (unsigned)f2bf(acc[6])  | ((unsigned)f2bf(acc[7])  << 16);
        pk1.x = (unsigned)f2bf(acc[8])  | ((unsigned)f2bf(acc[9])  << 16);
        pk1.y = (unsigned)f2bf(acc[10]) | ((unsigned)f2bf(acc[11]) << 16);
        pk1.z = (unsigned)f2bf(acc[12]) | ((unsigned)f2bf(acc[13]) << 16);
        pk1.w = (unsigned)f2bf(acc[14]) | ((unsigned)f2bf(acc[15]) << 16);
        *(uint4*)&aggs[ln * 72 + sl * 16] = pk0;
        *(uint4*)&aggs[ln * 72 + sl * 16 + 8] = pk1;
    }
    __syncthreads();

    // MFMA: 4 waves, wave w computes rows w*16..w*16+15: [16x64] @ [64x64]
    int wave = tid >> 6;
    int lane = tid & 63;
    int m = lane & 15, q = lane >> 4;
    int row = wave * 16 + m;
    f32x4 c2[4] = {{0.f,0.f,0.f,0.f},{0.f,0.f,0.f,0.f},{0.f,0.f,0.f,0.f},{0.f,0.f,0.f,0.f}};
    #pragma unroll
    for (int kk = 0; kk < 2; ++kk) {
        short8 afrag = *(const short8*)&aggs[row * 72 + kk * 32 + q * 8];
        #pragma unroll
        for (int nt = 0; nt < 4; ++nt) {
            const short8* bp = (const short8*)&Wt[(nt * 16 + m) * 72 + kk * 32 + q * 8];
            c2[nt] = __builtin_amdgcn_mfma_f32_16x16x32_bf16(afrag, *bp, c2[nt], 0, 0, 0);
        }
    }
    #pragma unroll
    for (int reg = 0; reg < 4; ++reg) {
        int nd = blockIdx.x * 64 + wave * 16 + q * 4 + reg;
        if (nd < NN) {
            #pragma unroll
            for (int nt = 0; nt < 4; ++nt)
                hout2[(long)nd * 64 + nt * 16 + m] = f2bf(c2[nt][reg]);
        }
    }
}

// ---------- final aggregation: 4 lanes/node, fp32 out ------------------------
__global__ __launch_bounds__(256) void k_agg2(const unsigned* __restrict__ rowinfo,
                                              const int* __restrict__ esrc,
                                              const unsigned short* __restrict__ h,
                                              const float* __restrict__ dinv,
                                              const float* __restrict__ bias,
                                              const float* __restrict__ alpha,
                                              float* __restrict__ out) {
    int sl = threadIdx.x & 3;
    int node = blockIdx.x * 64 + (threadIdx.x >> 2);
    if (node >= NN) return;
    unsigned u = rowinfo[node];
    int start = (int)(u >> 11);
    int cnt = (int)(u & 2047u);
    float dn = dinv[node];
    const unsigned short* hc = h + sl * 16;

    float acc[16];
    {   // self-loop
        const uint4* hp = (const uint4*)(hc + (long)node * 64);
        uint4 a = hp[0], b = hp[1];
        float d2 = dn * dn;
        #pragma unroll
        for (int j = 0; j < 16; ++j) acc[j] = 0.f;
        acc16(acc, a, b, d2);
    }
    agg_loop16(hc, esrc, dinv, start, cnt, dn, acc);

    float* op = out + (long)node * 64 + sl * 16;
    #pragma unroll
    for (int g = 0; g < 4; ++g) {
        float4 bb = *(const float4*)(bias + sl * 16 + g * 4);
        float4 aa = *(const float4*)(alpha + sl * 16 + g * 4);
        float vb[4] = {bb.x, bb.y, bb.z, bb.w};
        float va[4] = {aa.x, aa.y, aa.z, aa.w};
        float o[4];
        #pragma unroll
        for (int t = 0; t < 4; ++t) {
            float v = acc[g * 4 + t] + vb[t];
            o[t] = v >= 0.f ? v : va[t] * v;
        }
        *(float4*)(op + g * 4) = make_float4(o[0], o[1], o[2], o[3]);
    }
}

extern "C" void kernel_launch(void* const* d_in, const int* in_sizes, int n_in,
                              void* d_out, int out_size, void* d_ws, size_t ws_size,
                              hipStream_t stream) {
    const float* x     = (const float*)d_in[0];
    const int*   ei    = (const int*)d_in[1];
    const float* W1    = (const float*)d_in[2];
    const float* b1    = (const float*)d_in[3];
    const float* W2    = (const float*)d_in[4];
    const float* b2    = (const float*)d_in[5];
    const float* alpha = (const float*)d_in[6];
    float* out = (float*)d_out;

    char* ws = (char*)d_ws;
    float*    dinv      = (float*)(ws);                      //        0: 400,384
    unsigned* rowinfo   = (unsigned*)(ws + 400384);          //   400384: 400,384
    int*      bcur      = (int*)(ws + 800768);               //   800768: 2,048
    int*      esrc      = (int*)(ws + 802816);               //   802816: 8,007,680 (391*CAP)
    unsigned short* hbf = (unsigned short*)(ws + 8810496);   //  8810496: 12,800,000
    unsigned* ebuf      = (unsigned*)(ws + 21610496);        // 21610496: region max(8.0M, 12.8M)
    unsigned short* hbf2 = (unsigned short*)(ws + 21610496); // alias ebuf (dead after k_build)
    // total: 34,410,496 B

    (void)hipMemsetAsync(bcur, 0, NBUCK * sizeof(int), stream);
    // edge partition (782 blocks, single-pass) overlapped with x@W1 (1563 blocks)
    k_fat<<<PBLOCKS + MMBLOCKS, 256, 0, stream>>>(ei, bcur, ebuf, x, W1, hbf);
    k_build<<<NBUCK, 256, 0, stream>>>(bcur, ebuf, rowinfo, dinv, esrc);
    // layer-1 agg fused with layer-2 matmul (h2 -> hbf2, aliases dead ebuf)
    k_aggmm<<<(NN + 63) / 64, 256, 0, stream>>>(rowinfo, esrc, hbf, dinv, b1, alpha, W2, hbf2);
    // layer-2 aggregation -> fp32 out
    k_agg2<<<(NN + 63) / 64, 256, 0, stream>>>(rowinfo, esrc, hbf2, dinv, b2, alpha, out);
}

// Round 15
// 224.228 us; speedup vs baseline: 1.0507x; 1.0507x over previous
//
#include <hip/hip_runtime.h>
#include <hip/hip_bf16.h>

#define NN 100000
#define NE 1600000
#define NBUCK 391   // ceil(NN / 256)
#define CAP 5120    // per-bucket edge capacity (expected 4096, sigma~64)
#define CHUNK 2048
#define PBLOCKS 782   // ceil(NE / CHUNK)
#define MMBLOCKS 1563 // ceil(NN / 64)

typedef __attribute__((ext_vector_type(8))) short short8;
typedef __attribute__((ext_vector_type(4))) float f32x4;

static __device__ __forceinline__ unsigned short f2bf(float f) {
    unsigned u = __float_as_uint(f);
    unsigned r = (u + 0x7fffu + ((u >> 16) & 1u)) >> 16;
    return (unsigned short)r;
}
static __device__ __forceinline__ float bf_lo(unsigned u) {
    return __uint_as_float(u << 16);
}
static __device__ __forceinline__ float bf_hi(unsigned u) {
    return __uint_as_float(u & 0xffff0000u);
}
static __device__ __forceinline__ void acc8(float* acc, uint4 v, float nm) {
    acc[0] += bf_lo(v.x) * nm; acc[1] += bf_hi(v.x) * nm;
    acc[2] += bf_lo(v.y) * nm; acc[3] += bf_hi(v.y) * nm;
    acc[4] += bf_lo(v.z) * nm; acc[5] += bf_hi(v.z) * nm;
    acc[6] += bf_lo(v.w) * nm; acc[7] += bf_hi(v.w) * nm;
}

// shared aggregation loop: accumulates neighbors into acc[8] (unroll-4, proven R7/R8)
static __device__ __forceinline__ void agg_loop(const unsigned short* hc,
                                                const int* __restrict__ esrc,
                                                const float* __restrict__ dinv,
                                                int start, int cnt, float dn,
                                                float* acc) {
    int i = 0;
    for (; i + 4 <= cnt; i += 4) {
        int s0 = esrc[start + i];
        int s1 = esrc[start + i + 1];
        int s2 = esrc[start + i + 2];
        int s3 = esrc[start + i + 3];
        float n0 = dinv[s0] * dn, n1 = dinv[s1] * dn;
        float n2 = dinv[s2] * dn, n3 = dinv[s3] * dn;
        uint4 w0 = *(const uint4*)(hc + (long)s0 * 64);
        uint4 w1 = *(const uint4*)(hc + (long)s1 * 64);
        uint4 w2 = *(const uint4*)(hc + (long)s2 * 64);
        uint4 w3 = *(const uint4*)(hc + (long)s3 * 64);
        acc8(acc, w0, n0); acc8(acc, w1, n1); acc8(acc, w2, n2); acc8(acc, w3, n3);
    }
    for (; i < cnt; ++i) {
        int s0 = esrc[start + i];
        float n0 = dinv[s0] * dn;
        uint4 w0 = *(const uint4*)(hc + (long)s0 * 64);
        acc8(acc, w0, n0);
    }
}

// ---------- FAT: blocks [0,PBLOCKS) = edge partition (1-pass); rest = x@W1 ----
// bucket = dst >> 8; pack = (src<<8)|(dst&255)
__global__ __launch_bounds__(256) void k_fat(const int* __restrict__ ei,
                                             int* __restrict__ bcur,
                                             unsigned* __restrict__ ebuf,
                                             const float* __restrict__ x,
                                             const float* __restrict__ W1,
                                             unsigned short* __restrict__ hout) {
    __shared__ __attribute__((aligned(16))) unsigned char smem[17408];  // max(mm Wt 64*136*2, part 2*391*4)
    int tid = threadIdx.x;
    if (blockIdx.x < PBLOCKS) {
        int* lh = (int*)smem;
        int* lbase = lh + NBUCK;
        int e0 = blockIdx.x * CHUNK;
        for (int i = tid; i < NBUCK; i += 256) lh[i] = 0;
        __syncthreads();
        int bs[8]; int rs[8]; unsigned ps[8];
        #pragma unroll
        for (int k = 0; k < 8; ++k) {
            int e = e0 + k * 256 + tid;
            bs[k] = -1;
            if (e < NE) {
                int d = ei[NE + e];
                int s = ei[e];
                int b = d >> 8;
                bs[k] = b;
                rs[k] = atomicAdd(&lh[b], 1);      // local rank (single LDS pass)
                ps[k] = ((unsigned)s << 8) | (unsigned)(d & 255);
            }
        }
        __syncthreads();
        for (int i = tid; i < NBUCK; i += 256) {
            int c = lh[i];
            lbase[i] = c ? atomicAdd(&bcur[i], c) : 0;  // within-bucket offset
        }
        __syncthreads();
        #pragma unroll
        for (int k = 0; k < 8; ++k) {
            if (bs[k] >= 0) {
                int pos = lbase[bs[k]] + rs[k];
                if (pos < CAP)  // safety clamp; never hit for uniform input
                    ebuf[(long)bs[k] * CAP + pos] = ps[k];
            }
        }
    } else {
        // ---- mm128: h1 = x @ W1 -> bf16 ----
        constexpr int K = 128, KP = K + 8;
        unsigned short* Wt = (unsigned short*)smem;  // 64 * 136
        for (int idx = tid; idx < K * 64; idx += 256) {
            int k = idx >> 6, n = idx & 63;
            Wt[n * KP + k] = f2bf(W1[idx]);
        }
        __syncthreads();
        int wave = tid >> 6, lane = tid & 63;
        int m = lane & 15, q = lane >> 4;
        int n0 = (blockIdx.x - PBLOCKS) * 64 + wave * 16;
        f32x4 acc[4] = {{0.f,0.f,0.f,0.f},{0.f,0.f,0.f,0.f},{0.f,0.f,0.f,0.f},{0.f,0.f,0.f,0.f}};
        int row = n0 + m;
        int rowc = row < NN ? row : NN - 1;
        const float* xr = x + (long)rowc * K;
        #pragma unroll
        for (int kk = 0; kk < K / 32; ++kk) {
            const float4* p = (const float4*)(xr + kk * 32 + q * 8);
            float4 v0 = p[0], v1 = p[1];
            float xv[8] = {v0.x, v0.y, v0.z, v0.w, v1.x, v1.y, v1.z, v1.w};
            short8 afrag;
            #pragma unroll
            for (int i2 = 0; i2 < 8; ++i2) afrag[i2] = (short)f2bf(xv[i2]);
            #pragma unroll
            for (int nt = 0; nt < 4; ++nt) {
                const short8* bp = (const short8*)&Wt[(nt * 16 + m) * KP + kk * 32 + q * 8];
                acc[nt] = __builtin_amdgcn_mfma_f32_16x16x32_bf16(afrag, *bp, acc[nt], 0, 0, 0);
            }
        }
        // D layout: col=lane&15, row=(lane>>4)*4+reg  [m89-verified]
        #pragma unroll
        for (int reg = 0; reg < 4; ++reg) {
            int node = n0 + q * 4 + reg;
            if (node < NN) {
                #pragma unroll
                for (int nt = 0; nt < 4; ++nt)
                    hout[(long)node * 64 + nt * 16 + m] = f2bf(acc[nt][reg]);
            }
        }
    }
}

// one block (256 thr) per bucket, single ebuf pass with register stash.
// NEW: edges within each node's segment are sorted by src-tile (tile = src>>14,
// 7 tiles of 2 MB of h) so all concurrent agg waves walk the same L2-resident
// h-slice at the same time. key = (dst_local<<3)|tile; kstart[key] = start.
// rowinfo[node] = (start << 11) | degree   (start < 2^21, deg < 2^11)
__global__ __launch_bounds__(256) void k_build(const int* __restrict__ bcur,
                                               const unsigned* __restrict__ ebuf,
                                               unsigned* __restrict__ rowinfo,
                                               float* __restrict__ dinv,
                                               int* __restrict__ esrc) {
    __shared__ int cnt[2048];
    __shared__ int kstart[2048];
    __shared__ int wsum[4];
    int tid = threadIdx.x;
    int base = blockIdx.x * CAP;
    int nedge = bcur[blockIdx.x];
    if (nedge > CAP) nedge = CAP;
    #pragma unroll
    for (int t = 0; t < 8; ++t) cnt[(tid << 3) | t] = 0;
    __syncthreads();
    int st[20];      // (rank<<11) | key, or -1
    int ssrc[20];    // src node id
    #pragma unroll
    for (int k = 0; k < 20; ++k) {
        int j = tid + k * 256;
        st[k] = -1;
        if (j < nedge) {
            unsigned p = ebuf[base + j];
            int dl = (int)(p & 255u);
            int s = (int)(p >> 8);
            int key = (dl << 3) | (s >> 14);
            int r = atomicAdd(&cnt[key], 1);
            st[k] = (r << 11) | key;
            ssrc[k] = s;
        }
    }
    __syncthreads();
    // thread tid owns node tid: serial scan over its 8 tile counts
    int c[8];
    int v = 0;
    #pragma unroll
    for (int t = 0; t < 8; ++t) { c[t] = cnt[(tid << 3) | t]; v += c[t]; }
    int lane = tid & 63;
    int incl = v;
    #pragma unroll
    for (int off = 1; off < 64; off <<= 1) {
        int t = __shfl_up(incl, off, 64);
        if (lane >= off) incl += t;
    }
    if (lane == 63) wsum[tid >> 6] = incl;
    __syncthreads();
    if (tid == 0) {
        int a = 0;
        #pragma unroll
        for (int w = 0; w < 4; ++w) { int t = wsum[w]; wsum[w] = a; a += t; }
    }
    __syncthreads();
    int ex = incl - v + wsum[tid >> 6];
    int node = blockIdx.x * 256 + tid;
    if (node < NN) {
        rowinfo[node] = ((unsigned)(base + ex) << 11) | (unsigned)v;
        dinv[node] = rsqrtf((float)(v + 1));  // +1 self-loop
    }
    int off = base + ex;
    #pragma unroll
    for (int t = 0; t < 8; ++t) { kstart[(tid << 3) | t] = off; off += c[t]; }
    __syncthreads();
    #pragma unroll
    for (int k = 0; k < 20; ++k) {
        if (st[k] >= 0)
            esrc[kstart[st[k] & 2047] + (st[k] >> 11)] = ssrc[k];
    }
}

// ---------- fused: layer-1 agg (32 nodes/block) + h2 = prelu(agg1)@W2 --------
// NN % 32 == 0 so every block is full.
__global__ __launch_bounds__(256) void k_aggmm(const unsigned* __restrict__ rowinfo,
                                               const int* __restrict__ esrc,
                                               const unsigned short* __restrict__ h,
                                               const float* __restrict__ dinv,
                                               const float* __restrict__ bias,
                                               const float* __restrict__ alpha,
                                               const float* __restrict__ W2,
                                               unsigned short* __restrict__ hout2) {
    __shared__ unsigned short Wt[64 * 72];    // W2 staged: Wt[n*72+k]
    __shared__ unsigned short aggs[32 * 72];  // 32 node-rows of bf16 agg (+8 pad)
    int tid = threadIdx.x;
    for (int idx = tid; idx < 64 * 64; idx += 256) {
        int k = idx >> 6, n = idx & 63;
        Wt[n * 72 + k] = f2bf(W2[idx]);
    }
    int sl = tid & 7;
    int ln = tid >> 3;                  // 0..31 local node
    int node = blockIdx.x * 32 + ln;
    unsigned u = rowinfo[node];
    int start = (int)(u >> 11);
    int cnt = (int)(u & 2047u);
    float dn = dinv[node];
    const unsigned short* hc = h + sl * 8;

    float acc[8];
    {   // self-loop
        uint4 hw = *(const uint4*)(hc + (long)node * 64);
        float d2 = dn * dn;
        acc[0] = bf_lo(hw.x) * d2; acc[1] = bf_hi(hw.x) * d2;
        acc[2] = bf_lo(hw.y) * d2; acc[3] = bf_hi(hw.y) * d2;
        acc[4] = bf_lo(hw.z) * d2; acc[5] = bf_hi(hw.z) * d2;
        acc[6] = bf_lo(hw.w) * d2; acc[7] = bf_hi(hw.w) * d2;
    }
    agg_loop(hc, esrc, dinv, start, cnt, dn, acc);

    float4 blo = *(const float4*)(bias + sl * 8);
    float4 bhi = *(const float4*)(bias + sl * 8 + 4);
    float4 alo = *(const float4*)(alpha + sl * 8);
    float4 ahi = *(const float4*)(alpha + sl * 8 + 4);
    float bb[8] = {blo.x, blo.y, blo.z, blo.w, bhi.x, bhi.y, bhi.z, bhi.w};
    float aa[8] = {alo.x, alo.y, alo.z, alo.w, ahi.x, ahi.y, ahi.z, ahi.w};
    #pragma unroll
    for (int j = 0; j < 8; ++j) {
        float v = acc[j] + bb[j];
        acc[j] = v >= 0.f ? v : aa[j] * v;
    }
    uint4 pk;
    pk.x = (unsigned)f2bf(acc[0]) | ((unsigned)f2bf(acc[1]) << 16);
    pk.y = (unsigned)f2bf(acc[2]) | ((unsigned)f2bf(acc[3]) << 16);
    pk.z = (unsigned)f2bf(acc[4]) | ((unsigned)f2bf(acc[5]) << 16);
    pk.w = (unsigned)f2bf(acc[6]) | ((unsigned)f2bf(acc[7]) << 16);
    *(uint4*)&aggs[ln * 72 + sl * 8] = pk;
    __syncthreads();

    // MFMA: waves 0,1 compute 16 rows each: [16x64] @ [64x64]
    int wave = tid >> 6;
    if (wave < 2) {
        int lane = tid & 63;
        int m = lane & 15, q = lane >> 4;
        int row = wave * 16 + m;
        f32x4 c2[4] = {{0.f,0.f,0.f,0.f},{0.f,0.f,0.f,0.f},{0.f,0.f,0.f,0.f},{0.f,0.f,0.f,0.f}};
        #pragma unroll
        for (int kk = 0; kk < 2; ++kk) {
            short8 afrag = *(const short8*)&aggs[row * 72 + kk * 32 + q * 8];
            #pragma unroll
            for (int nt = 0; nt < 4; ++nt) {
                const short8* bp = (const short8*)&Wt[(nt * 16 + m) * 72 + kk * 32 + q * 8];
                c2[nt] = __builtin_amdgcn_mfma_f32_16x16x32_bf16(afrag, *bp, c2[nt], 0, 0, 0);
            }
        }
        #pragma unroll
        for (int reg = 0; reg < 4; ++reg) {
            int nd = blockIdx.x * 32 + wave * 16 + q * 4 + reg;
            #pragma unroll
            for (int nt = 0; nt < 4; ++nt)
                hout2[(long)nd * 64 + nt * 16 + m] = f2bf(c2[nt][reg]);
        }
    }
}

// ---------- final aggregation: 8 lanes/node, fp32 out ------------------------
__global__ __launch_bounds__(256) void k_agg2(const unsigned* __restrict__ rowinfo,
                                              const int* __restrict__ esrc,
                                              const unsigned short* __restrict__ h,
                                              const float* __restrict__ dinv,
                                              const float* __restrict__ bias,
                                              const float* __restrict__ alpha,
                                              float* __restrict__ out) {
    int sl = threadIdx.x & 7;
    int node = blockIdx.x * 32 + (threadIdx.x >> 3);
    unsigned u = rowinfo[node];
    int start = (int)(u >> 11);
    int cnt = (int)(u & 2047u);
    float dn = dinv[node];
    const unsigned short* hc = h + sl * 8;

    float acc[8];
    {   // self-loop
        uint4 hw = *(const uint4*)(hc + (long)node * 64);
        float d2 = dn * dn;
        acc[0] = bf_lo(hw.x) * d2; acc[1] = bf_hi(hw.x) * d2;
        acc[2] = bf_lo(hw.y) * d2; acc[3] = bf_hi(hw.y) * d2;
        acc[4] = bf_lo(hw.z) * d2; acc[5] = bf_hi(hw.z) * d2;
        acc[6] = bf_lo(hw.w) * d2; acc[7] = bf_hi(hw.w) * d2;
    }
    agg_loop(hc, esrc, dinv, start, cnt, dn, acc);

    float4 blo = *(const float4*)(bias + sl * 8);
    float4 bhi = *(const float4*)(bias + sl * 8 + 4);
    float4 alo = *(const float4*)(alpha + sl * 8);
    float4 ahi = *(const float4*)(alpha + sl * 8 + 4);
    float bb[8] = {blo.x, blo.y, blo.z, blo.w, bhi.x, bhi.y, bhi.z, bhi.w};
    float aa[8] = {alo.x, alo.y, alo.z, alo.w, ahi.x, ahi.y, ahi.z, ahi.w};
    #pragma unroll
    for (int j = 0; j < 8; ++j) {
        float v = acc[j] + bb[j];
        acc[j] = v >= 0.f ? v : aa[j] * v;
    }
    float* op = out + (long)node * 64 + sl * 8;
    *(float4*)op = make_float4(acc[0], acc[1], acc[2], acc[3]);
    *(float4*)(op + 4) = make_float4(acc[4], acc[5], acc[6], acc[7]);
}

extern "C" void kernel_launch(void* const* d_in, const int* in_sizes, int n_in,
                              void* d_out, int out_size, void* d_ws, size_t ws_size,
                              hipStream_t stream) {
    const float* x     = (const float*)d_in[0];
    const int*   ei    = (const int*)d_in[1];
    const float* W1    = (const float*)d_in[2];
    const float* b1    = (const float*)d_in[3];
    const float* W2    = (const float*)d_in[4];
    const float* b2    = (const float*)d_in[5];
    const float* alpha = (const float*)d_in[6];
    float* out = (float*)d_out;

    char* ws = (char*)d_ws;
    float*    dinv      = (float*)(ws);                      //        0: 400,384
    unsigned* rowinfo   = (unsigned*)(ws + 400384);          //   400384: 400,384
    int*      bcur      = (int*)(ws + 800768);               //   800768: 2,048
    int*      esrc      = (int*)(ws + 802816);               //   802816: 8,007,680 (391*CAP)
    unsigned short* hbf = (unsigned short*)(ws + 8810496);   //  8810496: 12,800,000
    unsigned* ebuf      = (unsigned*)(ws + 21610496);        // 21610496: region max(8.0M, 12.8M)
    unsigned short* hbf2 = (unsigned short*)(ws + 21610496); // alias ebuf (dead after k_build)
    // total: 34,410,496 B

    (void)hipMemsetAsync(bcur, 0, NBUCK * sizeof(int), stream);
    // edge partition (782 blocks, single-pass) overlapped with x@W1 (1563 blocks)
    k_fat<<<PBLOCKS + MMBLOCKS, 256, 0, stream>>>(ei, bcur, ebuf, x, W1, hbf);
    k_build<<<NBUCK, 256, 0, stream>>>(bcur, ebuf, rowinfo, dinv, esrc);
    // layer-1 agg fused with layer-2 matmul (h2 -> hbf2, aliases dead ebuf)
    k_aggmm<<<NN / 32, 256, 0, stream>>>(rowinfo, esrc, hbf, dinv, b1, alpha, W2, hbf2);
    // layer-2 aggregation -> fp32 out
    k_agg2<<<NN / 32, 256, 0, stream>>>(rowinfo, esrc, hbf2, dinv, b2, alpha, out);
}